// Round 1
// baseline (5350.104 us; speedup 1.0000x reference)
//
#include <hip/hip_runtime.h>
#include <hip/hip_bf16.h>
#include <hip/hip_fp16.h>

#define LOG2E 1.4426950408889634f

constexpr int B_ = 256, T_ = 128, IN_ = 64, U_ = 256;
constexpr int UNFOLDS = 6;

// ---- workspace layout (bytes) ----
// Compressed edge format: 6 B/edge (pairs of edges share one entry).
//   cd entry (uint2): .x = half2(c0,c1), .y = half2(d0,d1)   [8 B / pair]
//   ws entry (uint):  half2(ws0,ws1), |ws| derived via sign-mask [4 B / pair]
constexpr size_t OFF_RCD = 0;        // uint2[32768]: recurrent {c,d} pairs (256 KB)
constexpr size_t OFF_RWS = 262144;   // uint [32768]: recurrent ws pairs   (128 KB)
constexpr size_t OFF_SCD = 393216;   // uint2[8192]:  sensory {c,d} pairs  (64 KB)
constexpr size_t OFF_SWS = 458752;   // uint [8192]:  sensory ws pairs     (32 KB)
constexpr size_t OFF_ELF = 491520;   // float[32768]: elapsed (B*T)        (128 KB)
constexpr size_t OFF_VEC = 622592;   // float[1536]: gl[0:256] glvl[256:512] cm[512:768]
                                     //              how[768:1024] hob[1024:1280]
                                     //              inw[1280:1344] inb[1344:1408] hb[1408]
// total ~629 KB

__device__ __forceinline__ float ldf(const void* p, int idx, bool isbf) {
  return isbf ? __bfloat162float(((const __hip_bfloat16*)p)[idx])
              : ((const float*)p)[idx];
}

// ---------------------------------------------------------------------------
// Prep: detect dtype from timespans word0 (all-ones: 0x3F803F80 => bf16),
// convert everything to dtype-free packed workspace (half-compressed tables).
// ---------------------------------------------------------------------------
__global__ __launch_bounds__(256) void ltc_prep(
    const void* tspan, const void* smu, const void* ssigma, const void* sw,
    const void* serev, const void* mu, const void* sigma, const void* w,
    const void* erev, const void* gleak, const void* vleak, const void* cm,
    const void* inw, const void* inb, const void* outw, const void* outb,
    const void* headw, const void* headb, char* __restrict__ ws) {
  const bool isbf = (((const unsigned*)tspan)[0] == 0x3F803F80u);
  const int idx = blockIdx.x * blockDim.x + threadIdx.x;

  uint2*    rcd = (uint2*)(ws + OFF_RCD);
  unsigned* rws = (unsigned*)(ws + OFF_RWS);
  uint2*    scd = (uint2*)(ws + OFF_SCD);
  unsigned* sws = (unsigned*)(ws + OFF_SWS);
  float*    elf = (float*)(ws + OFF_ELF);
  float*    vec = (float*)(ws + OFF_VEC);

  if (idx < (U_ * U_) / 2) {  // recurrent edge pairs: (i, jp) -> j0=2jp, j1=2jp+1
    const int i = idx >> 7, jp = idx & 127;
    const int e0 = i * U_ + 2 * jp, e1 = e0 + 1;
    float sg0 = ldf(sigma, e0, isbf), m0 = ldf(mu, e0, isbf);
    float w0  = ldf(w, e0, isbf),     er0 = ldf(erev, e0, isbf);
    float sg1 = ldf(sigma, e1, isbf), m1 = ldf(mu, e1, isbf);
    float w1  = ldf(w, e1, isbf),     er1 = ldf(erev, e1, isbf);
    __half2 C, D, W;
    C.x = __float2half_rn(sg0 * m0 * LOG2E); C.y = __float2half_rn(sg1 * m1 * LOG2E);
    D.x = __float2half_rn(sg0 * LOG2E);      D.y = __float2half_rn(sg1 * LOG2E);
    W.x = __float2half_rn(w0 * er0);         W.y = __float2half_rn(w1 * er1);
    rcd[idx] = make_uint2(__builtin_bit_cast(unsigned, C),
                          __builtin_bit_cast(unsigned, D));
    rws[idx] = __builtin_bit_cast(unsigned, W);
  }
  if (idx < (IN_ * U_) / 2) {  // sensory edge pairs
    const int i = idx >> 7, jp = idx & 127;
    const int e0 = i * U_ + 2 * jp, e1 = e0 + 1;
    float sg0 = ldf(ssigma, e0, isbf), m0 = ldf(smu, e0, isbf);
    float w0  = ldf(sw, e0, isbf),     er0 = ldf(serev, e0, isbf);
    float sg1 = ldf(ssigma, e1, isbf), m1 = ldf(smu, e1, isbf);
    float w1  = ldf(sw, e1, isbf),     er1 = ldf(serev, e1, isbf);
    __half2 C, D, W;
    C.x = __float2half_rn(sg0 * m0 * LOG2E); C.y = __float2half_rn(sg1 * m1 * LOG2E);
    D.x = __float2half_rn(sg0 * LOG2E);      D.y = __float2half_rn(sg1 * LOG2E);
    W.x = __float2half_rn(w0 * er0);         W.y = __float2half_rn(w1 * er1);
    scd[idx] = make_uint2(__builtin_bit_cast(unsigned, C),
                          __builtin_bit_cast(unsigned, D));
    sws[idx] = __builtin_bit_cast(unsigned, W);
  }
  if (idx < B_ * T_) elf[idx] = ldf(tspan, idx, isbf);
  if (idx < U_) {
    float gl = ldf(gleak, idx, isbf);
    float hw = ldf(headw, idx, isbf);
    vec[idx]        = gl;
    vec[256 + idx]  = gl * ldf(vleak, idx, isbf);
    vec[512 + idx]  = ldf(cm, idx, isbf);
    vec[768 + idx]  = ldf(outw, idx, isbf) * hw;
    vec[1024 + idx] = ldf(outb, idx, isbf) * hw;
  }
  if (idx < IN_) {
    vec[1280 + idx] = ldf(inw, idx, isbf);
    vec[1344 + idx] = ldf(inb, idx, isbf);
  }
  if (idx == 0) vec[1408] = ldf(headb, 0, isbf);
}

// one edge-pair: for k in {0,1}: s = 1/(1+exp2(c_k - d_k*v)),
//   n_k += ws_k*s, d_k += |ws_k|*s.  c,d,ws are f16; decode fuses into
//   v_fma_mix_f32 (f16 operand-select), so no extra cvt instructions.
__device__ __forceinline__ void edgepair(uint2 cd, unsigned uw, float vi,
                                         float& n0, float& dd0,
                                         float& n1, float& dd1) {
  const __half2 C  = __builtin_bit_cast(__half2, cd.x);
  const __half2 D  = __builtin_bit_cast(__half2, cd.y);
  const __half2 Wp = __builtin_bit_cast(__half2, uw);
  const __half2 Wa = __builtin_bit_cast(__half2, uw & 0x7fff7fffu);
  float t0 = fmaf(-__low2float(D),  vi, __low2float(C));
  float t1 = fmaf(-__high2float(D), vi, __high2float(C));
  float r0 = __builtin_amdgcn_rcpf(1.0f + __builtin_amdgcn_exp2f(t0));
  float r1 = __builtin_amdgcn_rcpf(1.0f + __builtin_amdgcn_exp2f(t1));
  n0  = fmaf(__low2float(Wp),  r0, n0);
  dd0 = fmaf(__low2float(Wa),  r0, dd0);
  n1  = fmaf(__high2float(Wp), r1, n1);
  dd1 = fmaf(__high2float(Wa), r1, dd1);
}

// ---------------------------------------------------------------------------
// Main: one workgroup per batch. 1024 threads = 128 j-pairs x 8 i-groups.
// ---------------------------------------------------------------------------
__global__ __launch_bounds__(1024, 1) void ltc_main(
    const void* __restrict__ x_ltc, const void* __restrict__ tspan,
    const char* __restrict__ ws, void* __restrict__ out) {
  __shared__ float4 red4[1024];
  __shared__ __attribute__((aligned(16))) float v_sh[U_];
  __shared__ float x_sh[IN_];

  const bool isbf = (((const unsigned*)tspan)[0] == 0x3F803F80u);
  const int b   = blockIdx.x;
  const int tid = threadIdx.x;
  const int jp  = tid & 127;   // j-pair: j0=2jp, j1=2jp+1
  const int g   = tid >> 7;    // i-group 0..7

  const uint2*    rcd2 = (const uint2*)(ws + OFF_RCD);  // [i*128+jp]
  const unsigned* rws1 = (const unsigned*)(ws + OFF_RWS);
  const uint2*    scd2 = (const uint2*)(ws + OFF_SCD);
  const unsigned* sws1 = (const unsigned*)(ws + OFF_SWS);
  const float*    elf  = (const float*)(ws + OFF_ELF);
  const float*    vec  = (const float*)(ws + OFF_VEC);

  float r_gl = 0.f, r_glvl = 0.f, r_cm = 0.f;
  if (tid < U_) {
    v_sh[tid] = 0.0f;
    r_gl   = vec[tid];
    r_glvl = vec[256 + tid];
    r_cm   = vec[512 + tid];
  }
  float r_inw = 0.f, r_inb = 0.f;
  if (tid < IN_) { r_inw = vec[1280 + tid]; r_inb = vec[1344 + tid]; }
  __syncthreads();

  float rn_s = 0.f, rd_s = 0.f, r_cmt = 0.f;

  for (int t = 0; t < T_; ++t) {
    if (tid < IN_) {
      float xv = ldf(x_ltc, (b * T_ + t) * IN_ + tid, isbf);
      x_sh[tid] = fmaf(xv, r_inw, r_inb);
    }
    __syncthreads();

    // ---- sensory: i in [g*8, g*8+8) ----
    {
      float n0 = 0.f, dd0 = 0.f, n1 = 0.f, dd1 = 0.f;
      const int i0 = g * 8;
#pragma unroll
      for (int k = 0; k < 8; ++k) {
        const int i = i0 + k;
        const float xi = x_sh[i];
        uint2    cd = scd2[i * 128 + jp];
        unsigned uw = sws1[i * 128 + jp];
        edgepair(cd, uw, xi, n0, dd0, n1, dd1);
      }
      red4[tid] = make_float4(n0, dd0, n1, dd1);
    }
    __syncthreads();
    if (tid < U_) {
      const int base = tid >> 1, odd = tid & 1;
      float wn = 0.f, wd = 0.f;
#pragma unroll
      for (int gg = 0; gg < 8; ++gg) {
        float4 p = red4[gg * 128 + base];
        wn += odd ? p.z : p.x;
        wd += odd ? p.w : p.y;
      }
      rn_s = wn; rd_s = wd;
      float el = elf[b * T_ + t];
      r_cmt = r_cm * (float)UNFOLDS * __builtin_amdgcn_rcpf(el);  // cm/(el/6)
    }
    __syncthreads();  // red4 reuse guard

    // ---- ODE unfolds: i in [g*32, g*32+32) ----
    for (int u = 0; u < UNFOLDS; ++u) {
      float n0 = 0.f, dd0 = 0.f, n1 = 0.f, dd1 = 0.f;
      const int i0 = g * 32;
      for (int ib4 = 0; ib4 < 32; ib4 += 4) {
        float4 v4 = *(const float4*)&v_sh[i0 + ib4];
#pragma unroll
        for (int k = 0; k < 4; ++k) {
          const int i = i0 + ib4 + k;
          const float vi = (k == 0) ? v4.x : (k == 1) ? v4.y : (k == 2) ? v4.z : v4.w;
          uint2    cd = rcd2[i * 128 + jp];
          unsigned uw = rws1[i * 128 + jp];
          edgepair(cd, uw, vi, n0, dd0, n1, dd1);
        }
      }
      red4[tid] = make_float4(n0, dd0, n1, dd1);
      __syncthreads();
      if (tid < U_) {
        const int base = tid >> 1, odd = tid & 1;
        float wn = rn_s, wd = rd_s;
#pragma unroll
        for (int gg = 0; gg < 8; ++gg) {
          float4 p = red4[gg * 128 + base];
          wn += odd ? p.z : p.x;
          wd += odd ? p.w : p.y;
        }
        float vj  = v_sh[tid];
        float num = fmaf(r_cmt, vj, r_glvl) + wn;
        float den = r_cmt + r_gl + wd + 1e-8f;
        v_sh[tid] = num * __builtin_amdgcn_rcpf(den);
      }
      __syncthreads();
    }
  }

  // ---- head: out[b] = sum_j v_j*how_j + hob_j, + hb ----
  float* redf = (float*)red4;
  float val = 0.f;
  if (tid < U_) val = fmaf(v_sh[tid], vec[768 + tid], vec[1024 + tid]);
  redf[tid] = val;
  __syncthreads();
  for (int s = 512; s > 0; s >>= 1) {
    if (tid < s) redf[tid] += redf[tid + s];
    __syncthreads();
  }
  if (tid == 0) {
    float o = redf[0] + vec[1408];
    if (isbf) ((__hip_bfloat16*)out)[b] = __float2bfloat16(o);
    else      ((float*)out)[b] = o;
  }
}

extern "C" void kernel_launch(void* const* d_in, const int* in_sizes, int n_in,
                              void* d_out, int out_size, void* d_ws, size_t ws_size,
                              hipStream_t stream) {
  (void)in_sizes; (void)n_in; (void)out_size; (void)ws_size;
  const void* x_ltc  = d_in[0];
  const void* tspan  = d_in[1];
  const void* smu    = d_in[2];
  const void* ssigma = d_in[3];
  const void* sw     = d_in[4];
  const void* serev  = d_in[5];
  const void* mu     = d_in[6];
  const void* sigma  = d_in[7];
  const void* w      = d_in[8];
  const void* erev   = d_in[9];
  const void* gleak  = d_in[10];
  const void* vleak  = d_in[11];
  const void* cmv    = d_in[12];
  const void* inw    = d_in[13];
  const void* inb    = d_in[14];
  const void* outw   = d_in[15];
  const void* outb   = d_in[16];
  const void* headw  = d_in[17];
  const void* headb  = d_in[18];

  // 128 blocks x 256 threads = 32768 covers: 32768 recurrent pairs,
  // 8192 sensory pairs, 32768 elapsed, 256-wide vec sections.
  ltc_prep<<<128, 256, 0, stream>>>(
      tspan, smu, ssigma, sw, serev, mu, sigma, w, erev,
      gleak, vleak, cmv, inw, inb, outw, outb, headw, headb, (char*)d_ws);

  ltc_main<<<B_, 1024, 0, stream>>>(x_ltc, tspan, (const char*)d_ws, d_out);
}